// Round 2
// baseline (682.714 us; speedup 1.0000x reference)
//
#include <hip/hip_runtime.h>
#include <hip/hip_bf16.h>

#define NB 2048
#define NL 128
#define ND 512

__device__ __forceinline__ float bf2f(unsigned int u) {
    union { unsigned int i; float f; } x;
    x.i = u << 16;
    return x.f;
}

// One block per batch element b. 256 threads = 4 waves.
// Phase 1: compute new_a_t[b, :] (length 128) in LDS, write (f32) to d_out tail.
// Phase 2: output[b, d] = sum_l new_a[l] * ie[b, l, d]; each wave covers 32
// contiguous rows; f32 accumulate; 4-way LDS reduction; f32 store.
// OUTPUT IS ALWAYS float32 (reference output dtype). Input dtype is probed:
// a_t rows are normalized to sum 1.0 — the bf16 interpretation of the first
// 128 halves sums to ~1.0 iff the tensors really are bf16.
__global__ __launch_bounds__(256, 4) void sa_kernel(
    const void* __restrict__ a_t_v,
    const void* __restrict__ r_t_v,
    const void* __restrict__ ie_v,
    const void* __restrict__ mask_v,
    float* __restrict__ out)
{
    const int b = blockIdx.x;
    const int tid = threadIdx.x;

    __shared__ float aS[NL], mS[NL], wsS[NL], naS[NL];
    __shared__ float partial[4][ND];
    __shared__ int flagS;
    __shared__ float r01S[2];

    // --- input dtype probe (first 256 B of a_t — in-bounds either way) ---
    if (tid < 64) {
        const unsigned short* hus = (const unsigned short*)a_t_v;
        float sbf = bf2f(hus[2 * tid]) + bf2f(hus[2 * tid + 1]);
        #pragma unroll
        for (int off = 32; off; off >>= 1) sbf += __shfl_down(sbf, off);
        if (tid == 0) flagS = (fabsf(sbf - 1.0f) < 0.05f) ? 1 : 0;
    }
    __syncthreads();
    const int isbf = flagS;

    // --- load row b of a_t, mask, r_t under the detected dtype ---
    if (isbf) {
        const unsigned short* aus = (const unsigned short*)a_t_v + (size_t)b * NL;
        const unsigned short* mus = (const unsigned short*)mask_v + (size_t)b * NL;
        if (tid < NL) { aS[tid] = bf2f(aus[tid]); mS[tid] = bf2f(mus[tid]); }
        if (tid == 0) {
            const unsigned short* rus = (const unsigned short*)r_t_v + (size_t)b * 2;
            r01S[0] = bf2f(rus[0]); r01S[1] = bf2f(rus[1]);
        }
    } else {
        const float* af = (const float*)a_t_v + (size_t)b * NL;
        const float* mf = (const float*)mask_v + (size_t)b * NL;
        if (tid < NL) { aS[tid] = af[tid]; mS[tid] = mf[tid]; }
        if (tid == 0) {
            const float* rf = (const float*)r_t_v + (size_t)b * 2;
            r01S[0] = rf[0]; r01S[1] = rf[1];
        }
    }
    __syncthreads();
    const float r0 = r01S[0], r1 = r01S[1];

    // ws[i] = a[i]*r1 + a[i+1]*r0, i in [0,126]
    if (tid < NL - 1) wsS[tid] = aS[tid] * r1 + aS[tid + 1] * r0;
    __syncthreads();

    // new_a[l] = (l==0 ? a0*r0 : mask[l]*ws[l-1]) + (l<127 ? (1-mask[l+1])*ws[l] : 0)
    if (tid < NL) {
        float v = (tid == 0) ? aS[0] * r0 : mS[tid] * wsS[tid - 1];
        if (tid < NL - 1) v += (1.0f - mS[tid + 1]) * wsS[tid];
        naS[tid] = v;
        out[(size_t)NB * ND + (size_t)b * NL + tid] = v;   // f32 tail: new_a_t
    }
    __syncthreads();

    // --- phase 2: weighted row-sum over input_embedding[b] ---
    const int w = tid >> 6;   // wave id 0..3 -> rows [w*32, w*32+32)
    const int c = tid & 63;   // lane
    float acc[8];
    #pragma unroll
    for (int j = 0; j < 8; ++j) acc[j] = 0.f;

    if (isbf) {
        // lane c owns d in [c*8, c*8+8): one 16 B load per row, wave covers 1 KiB row
        const uint4* base = (const uint4*)((const unsigned short*)ie_v + (size_t)b * NL * ND);
        #pragma unroll 8
        for (int i = 0; i < 32; ++i) {
            const int l = w * 32 + i;
            const float na = naS[l];
            uint4 v = base[(size_t)l * (ND / 8) + c];
            acc[0] = fmaf(na, bf2f(v.x & 0xffffu), acc[0]);
            acc[1] = fmaf(na, bf2f(v.x >> 16),     acc[1]);
            acc[2] = fmaf(na, bf2f(v.y & 0xffffu), acc[2]);
            acc[3] = fmaf(na, bf2f(v.y >> 16),     acc[3]);
            acc[4] = fmaf(na, bf2f(v.z & 0xffffu), acc[4]);
            acc[5] = fmaf(na, bf2f(v.z >> 16),     acc[5]);
            acc[6] = fmaf(na, bf2f(v.w & 0xffffu), acc[6]);
            acc[7] = fmaf(na, bf2f(v.w >> 16),     acc[7]);
        }
    } else {
        // acc[0..3] -> d = 4c+j (first 1 KiB of row), acc[4..7] -> d = 1024+4c+j;
        // both float4 loads are wave-contiguous (lane c -> row+16c B and row+1024+16c B)
        const float4* base = (const float4*)((const float*)ie_v + (size_t)b * NL * ND);
        #pragma unroll 4
        for (int i = 0; i < 32; ++i) {
            const int l = w * 32 + i;
            const float na = naS[l];
            float4 v0 = base[(size_t)l * (ND / 4) + c];
            float4 v1 = base[(size_t)l * (ND / 4) + 64 + c];
            acc[0] = fmaf(na, v0.x, acc[0]);
            acc[1] = fmaf(na, v0.y, acc[1]);
            acc[2] = fmaf(na, v0.z, acc[2]);
            acc[3] = fmaf(na, v0.w, acc[3]);
            acc[4] = fmaf(na, v1.x, acc[4]);
            acc[5] = fmaf(na, v1.y, acc[5]);
            acc[6] = fmaf(na, v1.z, acc[6]);
            acc[7] = fmaf(na, v1.w, acc[7]);
        }
    }

    if (isbf) {
        #pragma unroll
        for (int j = 0; j < 8; ++j) partial[w][c * 8 + j] = acc[j];
    } else {
        #pragma unroll
        for (int j = 0; j < 4; ++j) partial[w][4 * c + j] = acc[j];
        #pragma unroll
        for (int j = 0; j < 4; ++j) partial[w][256 + 4 * c + j] = acc[4 + j];
    }
    __syncthreads();

    #pragma unroll
    for (int k = 0; k < 2; ++k) {
        const int d = tid + k * 256;
        float s = partial[0][d] + partial[1][d] + partial[2][d] + partial[3][d];
        out[(size_t)b * ND + d] = s;   // f32 main output
    }
}

extern "C" void kernel_launch(void* const* d_in, const int* in_sizes, int n_in,
                              void* d_out, int out_size, void* d_ws, size_t ws_size,
                              hipStream_t stream) {
    (void)in_sizes; (void)n_in; (void)out_size; (void)d_ws; (void)ws_size;
    const void* a_t  = d_in[0];
    const void* r_t  = d_in[1];
    const void* ie   = d_in[2];
    const void* mask = d_in[3];
    // d_in[4] is `step` (unused by the math).
    sa_kernel<<<dim3(NB), dim3(256), 0, stream>>>(a_t, r_t, ie, mask, (float*)d_out);
}